// Round 1
// baseline (2125.936 us; speedup 1.0000x reference)
//
#include <hip/hip_runtime.h>

// ---------------------------------------------------------------------------
// EAGLE draft layer, MI355X/gfx950. Round 3.
// Changes vs round 2 (theory: 256-block GEMM launches run at 1 block/CU ->
// ~350-460us each on fc/down; flash_k LDS reads are 16-way bank-conflicted):
//  - fc merged to ONE gemm (grid 16x32=512 blocks) via stage-local 64MiB WB.
//  - down merged to ONE gemm (grid 16x32) via stage-local 86MiB WB.
//  - qkv merged to ONE gemm (grid 16x48=768 blocks).
//  - gemm __launch_bounds__(256,3): m97's proven 3-blocks/CU config (164 VGPR).
//  - flash_k: T2 XOR-swizzle on Qs/Ks/Vs via pre-swizzled global source
//    (global_load_lds writes linearly; source perm == read perm, rule #21).
// Arena repacked stage-locally; peak stays at the proven 174MiB footprint.
// ---------------------------------------------------------------------------

typedef unsigned short u16;
typedef __bf16 bf16x8 __attribute__((ext_vector_type(8)));
typedef float f32x4 __attribute__((ext_vector_type(4)));

#define S_LEN 2048
#define H_DIM 4096
#define NH 32
#define NKV 8
#define I_DIM 11008
#define QKV_N 6144
#define NEGF (-3.402823466e38f)

__device__ __forceinline__ u16 f2bf(float f) {
  unsigned u = __float_as_uint(f);
  unsigned r = u + 0x7fffu + ((u >> 16) & 1u);   // RNE
  return (u16)(r >> 16);
}
__device__ __forceinline__ float bf2f(u16 h) {
  return __uint_as_float(((unsigned)h) << 16);
}
__device__ __forceinline__ void async16(const void* g, void* l) {
  __builtin_amdgcn_global_load_lds((__attribute__((address_space(1))) void*)g,
                                   (__attribute__((address_space(3))) void*)l,
                                   16, 0, 0);
}

// ---------------------------------------------------------------------------
// fp32 -> bf16 weight conversion; n must be multiple of 2048 (8 elems/thread)
__global__ __launch_bounds__(256) void cvtw(const float* __restrict__ src,
                                            u16* __restrict__ dst) {
  size_t i = ((size_t)blockIdx.x * 256 + threadIdx.x) * 8;
  float4 f0 = *(const float4*)(src + i);
  float4 f1 = *(const float4*)(src + i + 4);
  uint4 pk;
  pk.x = (unsigned)f2bf(f0.x) | ((unsigned)f2bf(f0.y) << 16);
  pk.y = (unsigned)f2bf(f0.z) | ((unsigned)f2bf(f0.w) << 16);
  pk.z = (unsigned)f2bf(f1.x) | ((unsigned)f2bf(f1.y) << 16);
  pk.w = (unsigned)f2bf(f1.z) | ((unsigned)f2bf(f1.w) << 16);
  *(uint4*)(dst + i) = pk;
}

// concat([embeds, hidden]) -> bf16 [S, 2H]
__global__ __launch_bounds__(256) void cat_cvt(const float* __restrict__ emb,
                                               const float* __restrict__ hid,
                                               u16* __restrict__ cat) {
  int idx = (blockIdx.x * 256 + threadIdx.x) * 4;
  int s = idx >> 13;
  int c = idx & 8191;
  const float* src = (c < H_DIM) ? (emb + ((size_t)s << 12) + c)
                                 : (hid + ((size_t)s << 12) + (c - H_DIM));
  float4 f = *(const float4*)src;
  ushort4 o;
  o.x = f2bf(f.x); o.y = f2bf(f.y); o.z = f2bf(f.z); o.w = f2bf(f.w);
  *(ushort4*)(cat + idx) = o;
}

// ---------------------------------------------------------------------------
// RMSNorm: one block per row; fp32 in, bf16 out
__global__ __launch_bounds__(256) void rmsnorm_k(const float* __restrict__ x,
                                                 const float* __restrict__ w,
                                                 u16* __restrict__ out) {
  __shared__ float red[4];
  int row = blockIdx.x;
  int t = threadIdx.x;
  const float4* xr = (const float4*)(x + ((size_t)row << 12));
  const float4* wr = (const float4*)w;
  float4 v[4];
  float ss = 0.f;
#pragma unroll
  for (int i = 0; i < 4; ++i) {
    v[i] = xr[t + i * 256];
    ss += v[i].x * v[i].x + v[i].y * v[i].y + v[i].z * v[i].z + v[i].w * v[i].w;
  }
#pragma unroll
  for (int off = 32; off > 0; off >>= 1) ss += __shfl_down(ss, off);
  if ((t & 63) == 0) red[t >> 6] = ss;
  __syncthreads();
  float tot = red[0] + red[1] + red[2] + red[3];
  float inv = rsqrtf(tot * (1.0f / 4096.0f) + 1e-6f);
  u16* orow = out + ((size_t)row << 12);
#pragma unroll
  for (int i = 0; i < 4; ++i) {
    float4 wv = wr[t + i * 256];
    ushort4 o;
    o.x = f2bf(v[i].x * inv * wv.x);
    o.y = f2bf(v[i].y * inv * wv.y);
    o.z = f2bf(v[i].z * inv * wv.z);
    o.w = f2bf(v[i].w * inv * wv.w);
    *(ushort4*)(orow + (t + i * 256) * 4) = o;
  }
}

// ---------------------------------------------------------------------------
// RoPE + head-split: bf16 [s][6144] (col offset) -> bf16 [h][s][d]
template <int NHD>
__global__ __launch_bounds__(256) void rope_k(const u16* __restrict__ src,
                                              u16* __restrict__ dst,
                                              int coloff) {
  int idx = blockIdx.x * 256 + threadIdx.x;  // NHD*S*64
  int d = idx & 63;
  int s = (idx >> 6) & 2047;
  int h = idx >> 17;
  float invf = exp2f(-0.20762050593048f * (float)d);  // 10000^(-d/64)
  float freq = (float)s * invf;
  float sn, cs;
  sincosf(freq, &sn, &cs);
  size_t bi = (size_t)s * QKV_N + coloff + h * 128 + d;
  float x1 = bf2f(src[bi]), x2 = bf2f(src[bi + 64]);
  size_t bo = (size_t)h * S_LEN * 128 + (size_t)s * 128 + d;
  dst[bo] = f2bf(x1 * cs - x2 * sn);
  dst[bo + 64] = f2bf(x2 * cs + x1 * sn);
}

// V: bf16 [s][6144] (cols 5120..6143) -> bf16 transposed [h][d][s]
__global__ __launch_bounds__(256) void vtrans_k(const u16* __restrict__ vf,
                                                u16* __restrict__ vt) {
  int idx = blockIdx.x * 256 + threadIdx.x;  // NKV*128*2048
  int s = idx & 2047;
  int d = (idx >> 11) & 127;
  int h = idx >> 18;
  vt[idx] = vf[(size_t)s * QKV_N + 5120 + h * 128 + d];
}

// ---------------------------------------------------------------------------
// GEMM: C[m0+128, n0+128] tile of A_bf16[M,K] @ W_bf16[N,K]^T  (+epilogue)
// grid.x = M/128 (fast-moving: co-resident blocks share W slices for L2 reuse)
// grid.y = Nsub/128. 256 threads, 4 waves x (64x64), mfma 16x16x32, both tiles
// via global_load_lds (m97 structure). launch_bounds(256,3) = m97's proven
// 3-blocks/CU occupancy (164 VGPR there; cap here is 170).
enum { EP_F32 = 0, EP_BIAS = 1, EP_RES = 2, EP_SILU = 3, EP_MUL = 4, EP_BF16 = 5 };

template <int EP>
__global__ __launch_bounds__(256, 3)
void gemm_bb(const u16* __restrict__ A, const u16* __restrict__ W,
             void* __restrict__ Cout, const void* __restrict__ extra,
             int K, int ldc) {
  __shared__ u16 As[128 * 64];
  __shared__ u16 Bs[128 * 64];
  const int tid = threadIdx.x;
  const int wave = tid >> 6, lane = tid & 63;
  const int m0 = blockIdx.x << 7, n0 = blockIdx.y << 7;
  const int wm = (wave >> 1) << 6, wn = (wave & 1) << 6;
  const int lr = lane & 15, lq = lane >> 4;
  const int arow = lane >> 3, akk = (lane & 7) << 3;

  f32x4 acc[4][4] = {};

  for (int k0 = 0; k0 < K; k0 += 64) {
#pragma unroll
    for (int c = 0; c < 4; ++c) {
      int chunk = (wave << 2) + c;
      async16(A + (size_t)(m0 + chunk * 8 + arow) * K + (k0 + akk), &As[chunk << 9]);
      async16(W + (size_t)(n0 + chunk * 8 + arow) * K + (k0 + akk), &Bs[chunk << 9]);
    }
    __syncthreads();   // compiler drains vmcnt before s_barrier
#pragma unroll
    for (int ks = 0; ks < 2; ++ks) {
      bf16x8 a[4], b[4];
#pragma unroll
      for (int i = 0; i < 4; ++i)
        a[i] = *(const bf16x8*)&As[(wm + i * 16 + lr) * 64 + (ks * 32 + lq * 8)];
#pragma unroll
      for (int j = 0; j < 4; ++j)
        b[j] = *(const bf16x8*)&Bs[(wn + j * 16 + lr) * 64 + (ks * 32 + lq * 8)];
#pragma unroll
      for (int i = 0; i < 4; ++i)
#pragma unroll
        for (int j = 0; j < 4; ++j)
          acc[i][j] = __builtin_amdgcn_mfma_f32_16x16x32_bf16(a[i], b[j], acc[i][j], 0, 0, 0);
    }
    __syncthreads();
  }

  float* cf = (float*)Cout;
  u16* cb = (u16*)Cout;
  const float* bias = (const float*)extra;
  const float* res = (const float*)extra;
  const u16* oth = (const u16*)extra;
#pragma unroll
  for (int i = 0; i < 4; ++i) {
#pragma unroll
    for (int j = 0; j < 4; ++j) {
      int gn = n0 + wn + j * 16 + lr;
      int gmb = m0 + wm + i * 16 + lq * 4;
#pragma unroll
      for (int r = 0; r < 4; ++r) {
        size_t off = (size_t)(gmb + r) * ldc + gn;
        float v = acc[i][j][r];
        if constexpr (EP == EP_BIAS) {
          cf[off] = v + bias[gn];
        } else if constexpr (EP == EP_F32) {
          cf[off] = v;
        } else if constexpr (EP == EP_RES) {
          cf[off] = v + res[off];
        } else if constexpr (EP == EP_SILU) {
          cb[off] = f2bf(v / (1.0f + __expf(-v)));
        } else if constexpr (EP == EP_MUL) {
          cb[off] = f2bf(v * bf2f(oth[off]));   // in-place over gate-act
        } else {  // EP_BF16
          cb[off] = f2bf(v);
        }
      }
    }
  }
}

// ---------------------------------------------------------------------------
// Flash attention: block = (q-tile of 64 rows, head). 4 waves x 16 q-rows.
// T2 XOR-swizzle on Qs/Ks/Vs: global_load_lds writes linearly, so the 16B
// source chunk index is XOR'd with (row&7) and the SAME XOR is applied on the
// ds_read byte offset (rule #21: source perm == read perm). This turns the
// 16-way bank conflict of stride-256B/128B row reads into a free 2-way.
__global__ __launch_bounds__(256, 2)
void flash_k(const u16* __restrict__ qr, const u16* __restrict__ kr,
             const u16* __restrict__ vt, const float* __restrict__ amask,
             u16* __restrict__ ao) {
  __shared__ u16 Qs[64 * 128];
  __shared__ u16 Ks[64 * 128];
  __shared__ u16 Vs[128 * 64];
  __shared__ u16 Ps[4][16 * 72];
  const int tid = threadIdx.x;
  const int wave = tid >> 6, lane = tid & 63;
  const int lr = lane & 15, lq = lane >> 4;
  const int qt0 = blockIdx.x << 6;
  const int h = blockIdx.y;
  const int hk = h >> 2;           // GQA: n_rep = 4
  const float scale = 0.08838834764831845f;  // 1/sqrt(128)

  const u16* qbase = qr + ((size_t)h * S_LEN + qt0) * 128;
#pragma unroll
  for (int c = 0; c < 4; ++c) {
    int chunk = (wave << 2) + c;
    int row = (chunk << 2) + (lane >> 4);               // q-row in tile
    int swz = (((lane & 15) ^ (row & 7)) << 3);         // swizzled elem col
    async16(qbase + (size_t)row * 128 + swz, &Qs[chunk << 9]);
  }

  const u16* kbase = kr + (size_t)hk * S_LEN * 128;
  const u16* vbase = vt + (size_t)hk * 128 * S_LEN;

  float m_i[4], l_i[4];
#pragma unroll
  for (int r = 0; r < 4; ++r) { m_i[r] = -__builtin_inff(); l_i[r] = 0.f; }
  f32x4 o[8] = {};
  const int qrow0 = qt0 + wave * 16 + lq * 4;

  for (int kt = 0; kt <= qt0; kt += 64) {
    __syncthreads();
#pragma unroll
    for (int c = 0; c < 4; ++c) {
      int chunk = (wave << 2) + c;
      int row = (chunk << 2) + (lane >> 4);             // k-row in tile
      int swz = (((lane & 15) ^ (row & 7)) << 3);
      async16(kbase + (size_t)(kt + row) * 128 + swz, &Ks[chunk << 9]);
      int d = (chunk << 3) + (lane >> 3);               // V row (=head dim)
      int soff = (((lane & 7) ^ (lane >> 3)) << 3);     // swizzled s-chunk
      async16(vbase + (size_t)d * S_LEN + kt + soff, &Vs[chunk << 9]);
    }
    __syncthreads();

    f32x4 sc[4] = {};
#pragma unroll
    for (int ks = 0; ks < 4; ++ks) {
      bf16x8 aq = *(const bf16x8*)&Qs[(wave * 16 + lr) * 128 +
                                      ((ks * 32 + lq * 8) ^ ((lr & 7) << 3))];
#pragma unroll
      for (int j = 0; j < 4; ++j) {
        bf16x8 bk = *(const bf16x8*)&Ks[(j * 16 + lr) * 128 +
                                        ((ks * 32 + lq * 8) ^ ((lr & 7) << 3))];
        sc[j] = __builtin_amdgcn_mfma_f32_16x16x32_bf16(aq, bk, sc[j], 0, 0, 0);
      }
    }

    float p[4][4];
    float mloc[4] = {-__builtin_inff(), -__builtin_inff(), -__builtin_inff(), -__builtin_inff()};
#pragma unroll
    for (int j = 0; j < 4; ++j) {
      int kpos = kt + j * 16 + lr;
      float pad = (amask[kpos] > 0.5f) ? 0.f : NEGF;
#pragma unroll
      for (int r = 0; r < 4; ++r) {
        float s = sc[j][r] * scale + pad;
        if (kpos > qrow0 + r) s += NEGF;
        p[j][r] = s;
        mloc[r] = fmaxf(mloc[r], s);
      }
    }
#pragma unroll
    for (int off = 1; off < 16; off <<= 1)
#pragma unroll
      for (int r = 0; r < 4; ++r) mloc[r] = fmaxf(mloc[r], __shfl_xor(mloc[r], off));

    float alpha[4], rs[4];
#pragma unroll
    for (int r = 0; r < 4; ++r) {
      float mnew = fmaxf(m_i[r], mloc[r]);
      alpha[r] = __expf(m_i[r] - mnew);
      m_i[r] = mnew;
      float s0 = 0.f;
#pragma unroll
      for (int j = 0; j < 4; ++j) {
        float e = __expf(p[j][r] - mnew);
        p[j][r] = e;
        s0 += e;
      }
      rs[r] = s0;
    }
#pragma unroll
    for (int off = 1; off < 16; off <<= 1)
#pragma unroll
      for (int r = 0; r < 4; ++r) rs[r] += __shfl_xor(rs[r], off);
#pragma unroll
    for (int r = 0; r < 4; ++r) l_i[r] = l_i[r] * alpha[r] + rs[r];
#pragma unroll
    for (int jj = 0; jj < 8; ++jj)
#pragma unroll
      for (int r = 0; r < 4; ++r) o[jj][r] *= alpha[r];

#pragma unroll
    for (int j = 0; j < 4; ++j)
#pragma unroll
      for (int r = 0; r < 4; ++r)
        Ps[wave][(lq * 4 + r) * 72 + j * 16 + lr] = f2bf(p[j][r]);

#pragma unroll
    for (int ks = 0; ks < 2; ++ks) {
      bf16x8 ap = *(const bf16x8*)&Ps[wave][lr * 72 + ks * 32 + lq * 8];
#pragma unroll
      for (int jj = 0; jj < 8; ++jj) {
        bf16x8 bv = *(const bf16x8*)&Vs[(jj * 16 + lr) * 64 +
                                        ((ks * 32 + lq * 8) ^ ((lr & 7) << 3))];
        o[jj] = __builtin_amdgcn_mfma_f32_16x16x32_bf16(ap, bv, o[jj], 0, 0, 0);
      }
    }
  }

#pragma unroll
  for (int r = 0; r < 4; ++r) {
    float invl = 1.0f / l_i[r];
    int srow = qrow0 + r;
#pragma unroll
    for (int jj = 0; jj < 8; ++jj)
      ao[(size_t)srow * H_DIM + h * 128 + jj * 16 + lr] = f2bf(o[jj][r] * invl);
  }
}

// ---------------------------------------------------------------------------
// Arena (MiB offsets; stage-local overlap, peak 174MiB == proven footprint):
//   X    @  0..32   f32 [S,H]             (live: fc -> end)
//   XN   @ 32..48   bf16 [S,H]            (innorm->qkv; postnorm->up)
//   CAT  @ 48..80   bf16 [S,2H]           (stage fc only)
//   WBfc @ 80..144  bf16 fc_w             (stage fc only)
//   WBq  @ 48..96   bf16 qkv_w            (stage qkv; CAT dead)
//   QKVo @ 96..120  bf16 [S,6144]         (qkv -> rope)
//   QR   @120..136  bf16 [NH,S,D]
//   KR   @136..140  bf16 [NKV,S,D]
//   VT   @140..144  bf16 [NKV,D,S]
//   AO   @144..160  bf16 [S,NH*D]
//   WBo  @ 48..80   bf16 o_w              (stage oproj)
//   WBgu @ 48..91   bf16 gate/up half     (stage gate/up)
//   GACT @131..174  bf16 [S,I]            (gate -> down)
//   WBdn @ 32..118  bf16 down_w FULL      (stage down; XN dead)
extern "C" void kernel_launch(void* const* d_in, const int* in_sizes, int n_in,
                              void* d_out, int out_size, void* d_ws, size_t ws_size,
                              hipStream_t stream) {
  const float* hid = (const float*)d_in[0];
  const float* emb = (const float*)d_in[1];
  const float* amask = (const float*)d_in[2];
  const float* fc_w = (const float*)d_in[3];
  const float* fc_b = (const float*)d_in[4];
  const float* in_nw = (const float*)d_in[5];
  const float* q_w = (const float*)d_in[6];
  const float* k_w = (const float*)d_in[7];
  const float* v_w = (const float*)d_in[8];
  const float* o_w = (const float*)d_in[9];
  const float* post_nw = (const float*)d_in[10];
  const float* gate_w = (const float*)d_in[11];
  const float* up_w = (const float*)d_in[12];
  const float* down_w = (const float*)d_in[13];
  (void)in_sizes; (void)n_in; (void)out_size; (void)ws_size;

  char* ws = (char*)d_ws;
  const size_t MiB = 1048576;
  float* X    = (float*)(ws + 0);
  u16* XN     = (u16*)(ws + 32 * MiB);
  u16* CAT    = (u16*)(ws + 48 * MiB);
  u16* WB_FC  = (u16*)(ws + 80 * MiB);
  u16* WB_QKV = (u16*)(ws + 48 * MiB);
  u16* QKVo   = (u16*)(ws + 96 * MiB);
  u16* QR     = (u16*)(ws + 120 * MiB);
  u16* KR     = (u16*)(ws + 136 * MiB);
  u16* VT     = (u16*)(ws + 140 * MiB);
  u16* AO     = (u16*)(ws + 144 * MiB);
  u16* WB_O   = (u16*)(ws + 48 * MiB);
  u16* WB_GU  = (u16*)(ws + 48 * MiB);
  u16* GACT   = (u16*)(ws + 131 * MiB);
  u16* WB_DN  = (u16*)(ws + 32 * MiB);

  // 1. concat -> bf16
  cat_cvt<<<dim3(16384), dim3(256), 0, stream>>>(emb, hid, CAT);

  // 2. fc (N=4096, K=8192) — single launch, 512 blocks
  cvtw<<<dim3(16384), dim3(256), 0, stream>>>(fc_w, WB_FC);
  gemm_bb<EP_BIAS><<<dim3(16, 32), dim3(256), 0, stream>>>(
      CAT, WB_FC, X, fc_b, 8192, H_DIM);

  // 3. input norm
  rmsnorm_k<<<dim3(2048), dim3(256), 0, stream>>>(X, in_nw, XN);

  // 4. fused QKV (N=6144, K=4096) — single launch, 768 blocks
  cvtw<<<dim3(8192), dim3(256), 0, stream>>>(q_w, WB_QKV);
  cvtw<<<dim3(2048), dim3(256), 0, stream>>>(k_w, WB_QKV + (size_t)4096 * 4096);
  cvtw<<<dim3(2048), dim3(256), 0, stream>>>(v_w, WB_QKV + (size_t)5120 * 4096);
  gemm_bb<EP_BF16><<<dim3(16, 48), dim3(256), 0, stream>>>(
      XN, WB_QKV, QKVo, nullptr, H_DIM, QKV_N);

  // 5. RoPE + head-split (q, k), transpose (v)
  rope_k<NH><<<dim3(16384), dim3(256), 0, stream>>>(QKVo, QR, 0);
  rope_k<NKV><<<dim3(4096), dim3(256), 0, stream>>>(QKVo, KR, 4096);
  vtrans_k<<<dim3(8192), dim3(256), 0, stream>>>(QKVo, VT);

  // 6. flash attention
  flash_k<<<dim3(32, 32), dim3(256), 0, stream>>>(QR, KR, VT, amask, AO);

  // 7. O-proj + residual (in-place X)
  cvtw<<<dim3(8192), dim3(256), 0, stream>>>(o_w, WB_O);
  gemm_bb<EP_RES><<<dim3(16, 32), dim3(256), 0, stream>>>(AO, WB_O, X, X, H_DIM, H_DIM);

  // 8. post norm
  rmsnorm_k<<<dim3(2048), dim3(256), 0, stream>>>(X, post_nw, XN);

  // 9/10. gate (silu) then up (mul, in place over GACT), N=11008 in halves of 5504
  for (int hh = 0; hh < 2; ++hh) {
    cvtw<<<dim3(11008), dim3(256), 0, stream>>>(gate_w + (size_t)hh * 5504 * 4096, WB_GU);
    gemm_bb<EP_SILU><<<dim3(16, 43), dim3(256), 0, stream>>>(
        XN, WB_GU, GACT + hh * 5504, nullptr, H_DIM, I_DIM);
  }
  for (int hh = 0; hh < 2; ++hh) {
    cvtw<<<dim3(11008), dim3(256), 0, stream>>>(up_w + (size_t)hh * 5504 * 4096, WB_GU);
    gemm_bb<EP_MUL><<<dim3(16, 43), dim3(256), 0, stream>>>(
        XN, WB_GU, GACT + hh * 5504, GACT + hh * 5504, H_DIM, I_DIM);
  }

  // 11. down + residual -> d_out (f32), single launch (N=4096, K=11008)
  cvtw<<<dim3(22016), dim3(256), 0, stream>>>(down_w, WB_DN);
  gemm_bb<EP_RES><<<dim3(16, 32), dim3(256), 0, stream>>>(
      GACT, WB_DN, (float*)d_out, X, I_DIM, H_DIM);
}